// Round 5
// baseline (223.696 us; speedup 1.0000x reference)
//
#include <hip/hip_runtime.h>
#include <hip/hip_bf16.h>

// PatchEmbed MFMA v3. f32 data (proven R1/R2). B=8,N=16384,M=2048,K=32.
//   pe_pack: W2/W3 f32 -> bf16 MFMA B-fragments in d_ws (80 KB).
//   pe_mfma: G=2 centers/block, 8192 blocks, 256 thr, LDS 24.6 KB,
//            __launch_bounds__(256,6) -> 6 blocks/CU (DS/VMEM latency hiding).
// v3 changes vs v2: w1/b1 in wave-uniform regs (no LDS broadcast reads, one
// barrier fewer); stage-3 folds rt-pairs in C-regs before the cross-lane max
// (16 shfls/wave instead of 32).

typedef __attribute__((ext_vector_type(8))) short bf16x8;
typedef __attribute__((ext_vector_type(4))) float f32x4v;

constexpr int Bn = 8, Nn = 16384, Mn = 2048, Kn = 32, EMB = 256;
constexpr int G = 2;              // centers per block
constexpr int ROWS = G * Kn;      // 64 rows per block

__device__ __forceinline__ unsigned short bfr(float x) {   // f32 -> bf16 RTN
    unsigned u = __float_as_uint(x);
    u += 0x7fffu + ((u >> 16) & 1u);
    return (unsigned short)(u >> 16);
}

__device__ __forceinline__ bf16x8 pack8(const float* v) {
    bf16x8 r;
    #pragma unroll
    for (int i = 0; i < 8; ++i) r[i] = (short)bfr(v[i]);
    return r;
}

// ---- kernel A: pack W2 (1024 frags) + W3 (4096 frags) into ws ----
__global__ __launch_bounds__(256) void pe_pack(
    const float* __restrict__ W2, const float* __restrict__ W3,
    uint4* __restrict__ ws)
{
    int gid = blockIdx.x * 256 + threadIdx.x;
    if (gid < 1024) {
        int e = gid, l = e & 63;
        int kt = (e >> 6) & 1, ct = (e >> 7) & 1, w = e >> 8;
        int q = l >> 4, n = l & 15;
        int ch = w * 32 + ct * 16 + n;
        const float* p = W2 + ch * 64 + kt * 32 + q * 8;
        float t[8];
        *(float4*)&t[0] = *(const float4*)p;
        *(float4*)&t[4] = *(const float4*)(p + 4);
        bf16x8 v = pack8(t);
        ws[e] = *(uint4*)&v;
    } else if (gid < 5120) {
        int e = gid - 1024, l = e & 63;
        int kt = (e >> 6) & 3, ct = (e >> 8) & 3, w = e >> 10;
        int q = l >> 4, n = l & 15;
        int ch = w * 64 + ct * 16 + n;
        const float* p = W3 + ch * 128 + kt * 32 + q * 8;
        float t[8];
        *(float4*)&t[0] = *(const float4*)p;
        *(float4*)&t[4] = *(const float4*)(p + 4);
        bf16x8 v = pack8(t);
        ws[1024 + e] = *(uint4*)&v;
    }
}

__global__ __launch_bounds__(256, 6) void pe_mfma(
    const float* __restrict__ xyz,      // (B,N,3)
    const float* __restrict__ centers,  // (B,M,3)
    const int*   __restrict__ idx,      // (B,M,K)
    const float* __restrict__ W1,       // (64,3)
    const float* __restrict__ b1,       // (64,)
    const float* __restrict__ b2,       // (128,)
    const float* __restrict__ b3,       // (256,)
    const uint4* __restrict__ wsf,      // packed W2/W3 fragments
    float*       __restrict__ out)      // (B,M,256)
{
    __shared__ uint4 h1v[ROWS * 64 * 2 / 16];    // 512 uint4  = 8 KB
    __shared__ uint4 h2v[ROWS * 128 * 2 / 16];   // 1024 uint4 = 16 KB

    const int tid = threadIdx.x;
    const int w   = tid >> 6;          // wave 0..3
    const int l   = tid & 63;
    const int q   = l >> 4;            // quad 0..3
    const int n   = l & 15;            // frag row/col index
    const int bm0 = blockIdx.x * G;

    // ---- B-fragments from ws (coalesced uint4) ----
    bf16x8 B2f[2][2];  float b2v[2];
    #pragma unroll
    for (int ct = 0; ct < 2; ++ct) {
        b2v[ct] = b2[w * 32 + ct * 16 + n];
        #pragma unroll
        for (int kt = 0; kt < 2; ++kt) {
            uint4 u = wsf[((w * 2 + ct) * 2 + kt) * 64 + l];
            B2f[ct][kt] = *(bf16x8*)&u;
        }
    }
    bf16x8 B3f[4][4];  float b3v[4];
    #pragma unroll
    for (int ct = 0; ct < 4; ++ct) {
        b3v[ct] = b3[w * 64 + ct * 16 + n];
        #pragma unroll
        for (int kt = 0; kt < 4; ++kt) {
            uint4 u = wsf[1024 + ((w * 4 + ct) * 4 + kt) * 64 + l];
            B3f[ct][kt] = *(bf16x8*)&u;
        }
    }

    // ---- w1/b1 wave-uniform registers (s_load path, no LDS) ----
    const int o4b = __builtin_amdgcn_readfirstlane((tid >> 6) * 4);
    float wr[12], br[4];
    {
        const float4* Wp = (const float4*)(W1 + o4b * 12);  // 16B-aligned
        float4 wa = Wp[0], wb = Wp[1], wc = Wp[2];
        wr[0]=wa.x; wr[1]=wa.y; wr[2]=wa.z; wr[3]=wa.w;
        wr[4]=wb.x; wr[5]=wb.y; wr[6]=wb.z; wr[7]=wb.w;
        wr[8]=wc.x; wr[9]=wc.y; wr[10]=wc.z; wr[11]=wc.w;
        float4 bb = *(const float4*)(b1 + o4b * 4);
        br[0]=bb.x; br[1]=bb.y; br[2]=bb.z; br[3]=bb.w;
    }

    // ---- gather + center-subtract (4 threads per row, redundant) ----
    const int r64 = tid & 63;                 // row 0..63
    {
        int bm = bm0 + (r64 >> 5);
        int bb = bm >> 11;
        int id = idx[(size_t)bm * Kn + (r64 & 31)];
        const float* p = xyz + ((size_t)bb * Nn + id) * 3;
        const float* c = centers + (size_t)bm * 3;
        float lx = p[0] - c[0], ly = p[1] - c[1], lz = p[2] - c[2];

        // ---- stage 1: thread computes 16 channels of its row ----
        float h[16];
        #pragma unroll
        for (int i = 0; i < 4; ++i) {
            h[4*i+0] = fmaxf(br[0] + lx*wr[0] + ly*wr[1]  + lz*wr[2], 0.f);
            // NOTE: channel group i uses weights (o4b+i)*12.. -> recompute idx
        }
        // correct per-group weights: group i covers channels (o4b+i)*4..+3,
        // weights W1[(o4b+i)*4 + c][3]. wr[] above only holds group 0's 12
        // floats -- load per group instead (still wave-uniform s_loads).
        #pragma unroll
        for (int i = 0; i < 4; ++i) {
            const float4* Wp = (const float4*)(W1 + (o4b + i) * 12);
            float4 wa = Wp[0], wb = Wp[1], wc = Wp[2];
            float b0, b1v_, b2_, b3_;
            {
                const float4 bb4 = *(const float4*)(b1 + (o4b + i) * 4);
                b0 = bb4.x; b1v_ = bb4.y; b2_ = bb4.z; b3_ = bb4.w;
            }
            h[4*i+0] = fmaxf(b0   + lx*wa.x + ly*wa.y + lz*wa.z, 0.f);
            h[4*i+1] = fmaxf(b1v_ + lx*wa.w + ly*wb.x + lz*wb.y, 0.f);
            h[4*i+2] = fmaxf(b2_  + lx*wb.z + ly*wb.w + lz*wc.x, 0.f);
            h[4*i+3] = fmaxf(b3_  + lx*wc.y + ly*wc.z + lz*wc.w, 0.f);
        }
        const int T = r64 >> 4, r = r64 & 15, j0 = (tid >> 6) * 2;
        #pragma unroll
        for (int jj = 0; jj < 2; ++jj) {
            bf16x8 v = pack8(&h[8 * jj]);
            h1v[T * 128 + (j0 + jj) * 16 + r] = *(uint4*)&v;
        }
    }
    __syncthreads();

    // ---- stage 2: h2 = relu(h1 @ W2^T + b2), wave owns 32 cols ----
    {
        ushort* h2s = (ushort*)h2v;
        #pragma unroll
        for (int rt = 0; rt < G * 2; ++rt) {
            uint4 a0u = h1v[rt * 128 + q * 16 + n];
            uint4 a1u = h1v[rt * 128 + (4 + q) * 16 + n];
            bf16x8 A0 = *(bf16x8*)&a0u, A1 = *(bf16x8*)&a1u;
            #pragma unroll
            for (int ct = 0; ct < 2; ++ct) {
                f32x4v c0 = {0.f, 0.f, 0.f, 0.f};
                c0 = __builtin_amdgcn_mfma_f32_16x16x32_bf16(A0, B2f[ct][0], c0, 0, 0, 0);
                c0 = __builtin_amdgcn_mfma_f32_16x16x32_bf16(A1, B2f[ct][1], c0, 0, 0, 0);
                int ch = w * 32 + ct * 16 + n;
                #pragma unroll
                for (int reg = 0; reg < 4; ++reg) {
                    float v = fmaxf(c0[reg] + b2v[ct], 0.f);
                    int rowl = q * 4 + reg;
                    h2s[rt * 2048 + (ch >> 3) * 128 + rowl * 8 + (ch & 7)] = bfr(v);
                }
            }
        }
    }
    __syncthreads();

    // ---- stage 3: wave owns 64 cols; fold rt-pair in regs, then 2 shfls ----
    {
        #pragma unroll
        for (int g = 0; g < G; ++g) {
            bf16x8 Ae[4], Ao[4];
            #pragma unroll
            for (int kt = 0; kt < 4; ++kt) {
                uint4 ae = h2v[(2*g)   * 256 + (kt * 4 + q) * 16 + n];
                uint4 ao = h2v[(2*g+1) * 256 + (kt * 4 + q) * 16 + n];
                Ae[kt] = *(bf16x8*)&ae;
                Ao[kt] = *(bf16x8*)&ao;
            }
            #pragma unroll
            for (int ct = 0; ct < 4; ++ct) {
                f32x4v Ce = {0.f, 0.f, 0.f, 0.f};
                f32x4v Co = {0.f, 0.f, 0.f, 0.f};
                #pragma unroll
                for (int kt = 0; kt < 4; ++kt) {
                    Ce = __builtin_amdgcn_mfma_f32_16x16x32_bf16(Ae[kt], B3f[ct][kt], Ce, 0, 0, 0);
                    Co = __builtin_amdgcn_mfma_f32_16x16x32_bf16(Ao[kt], B3f[ct][kt], Co, 0, 0, 0);
                }
                float v = fmaxf(fmaxf(fmaxf(Ce[0], Co[0]), fmaxf(Ce[1], Co[1])),
                                fmaxf(fmaxf(Ce[2], Co[2]), fmaxf(Ce[3], Co[3])));
                v = fmaxf(v, __shfl_xor(v, 16));
                v = fmaxf(v, __shfl_xor(v, 32));
                if (q == 0) {
                    out[(size_t)(bm0 + g) * EMB + w * 64 + ct * 16 + n] = v + b3v[ct];
                }
            }
        }
    }
}

extern "C" void kernel_launch(void* const* d_in, const int* in_sizes, int n_in,
                              void* d_out, int out_size, void* d_ws, size_t ws_size,
                              hipStream_t stream) {
    const float* xyz     = (const float*)d_in[0];
    const float* centers = (const float*)d_in[1];
    const int*   idx     = (const int*)  d_in[2];
    const float* W1      = (const float*)d_in[3];
    const float* b1      = (const float*)d_in[4];
    const float* W2      = (const float*)d_in[5];
    const float* b2      = (const float*)d_in[6];
    const float* W3      = (const float*)d_in[7];
    const float* b3      = (const float*)d_in[8];
    float*       out     = (float*)d_out;
    uint4*       ws      = (uint4*)d_ws;    // needs 5120*16 = 80 KB

    pe_pack<<<20, 256, 0, stream>>>(W2, W3, ws);
    pe_mfma<<<(Bn * Mn) / G, 256, 0, stream>>>(
        xyz, centers, idx, W1, b1, b2, b3, ws, out);
}

// Round 6
// 123.791 us; speedup vs baseline: 1.8070x; 1.8070x over previous
//
#include <hip/hip_runtime.h>
#include <hip/hip_bf16.h>

// PatchEmbed MFMA v4. f32 data (proven R1/R2). B=8,N=16384,M=2048,K=32.
//   pe_pack: W2/W3 f32 -> bf16 MFMA B-fragments in d_ws (80 KB).
//   pe_mfma: G=2 centers/block, 8192 blocks, 256 thr, LDS 24 KB.
// v4 = v3 with the spill fixed: __launch_bounds__(256,4). R5 showed (256,6)
// caps VGPR at ~85 -> B-fragments spill to scratch (FETCH 8->265 MB, 2.4x
// slower). Occupancy here must come from LDS (24KB -> 6 blocks/CU), never
// from a VGPR cap. Also: bf16 packing via v_cvt_pk_bf16_f32.

typedef __attribute__((ext_vector_type(8))) short bf16x8;
typedef __attribute__((ext_vector_type(4))) float f32x4v;

constexpr int Bn = 8, Nn = 16384, Mn = 2048, Kn = 32, EMB = 256;
constexpr int G = 2;              // centers per block
constexpr int ROWS = G * Kn;      // 64 rows per block

__device__ __forceinline__ unsigned pk2(float a, float b) {  // v_cvt_pk_bf16_f32
    float2 f; f.x = a; f.y = b;
    __hip_bfloat162 h = __float22bfloat162_rn(f);
    return *(unsigned*)&h;
}

__device__ __forceinline__ bf16x8 pack8(const float* v) {
    unsigned u0 = pk2(v[0], v[1]), u1 = pk2(v[2], v[3]);
    unsigned u2 = pk2(v[4], v[5]), u3 = pk2(v[6], v[7]);
    uint4 u = make_uint4(u0, u1, u2, u3);
    return *(bf16x8*)&u;
}

// ---- kernel A: pack W2 (1024 frags) + W3 (4096 frags) into ws ----
__global__ __launch_bounds__(256) void pe_pack(
    const float* __restrict__ W2, const float* __restrict__ W3,
    uint4* __restrict__ ws)
{
    int gid = blockIdx.x * 256 + threadIdx.x;
    if (gid < 1024) {
        int e = gid, l = e & 63;
        int kt = (e >> 6) & 1, ct = (e >> 7) & 1, w = e >> 8;
        int q = l >> 4, n = l & 15;
        int ch = w * 32 + ct * 16 + n;
        const float* p = W2 + ch * 64 + kt * 32 + q * 8;
        float t[8];
        *(float4*)&t[0] = *(const float4*)p;
        *(float4*)&t[4] = *(const float4*)(p + 4);
        bf16x8 v = pack8(t);
        ws[e] = *(uint4*)&v;
    } else if (gid < 5120) {
        int e = gid - 1024, l = e & 63;
        int kt = (e >> 6) & 3, ct = (e >> 8) & 3, w = e >> 10;
        int q = l >> 4, n = l & 15;
        int ch = w * 64 + ct * 16 + n;
        const float* p = W3 + ch * 128 + kt * 32 + q * 8;
        float t[8];
        *(float4*)&t[0] = *(const float4*)p;
        *(float4*)&t[4] = *(const float4*)(p + 4);
        bf16x8 v = pack8(t);
        ws[1024 + e] = *(uint4*)&v;
    }
}

__global__ __launch_bounds__(256, 4) void pe_mfma(
    const float* __restrict__ xyz,      // (B,N,3)
    const float* __restrict__ centers,  // (B,M,3)
    const int*   __restrict__ idx,      // (B,M,K)
    const float* __restrict__ W1,       // (64,3)
    const float* __restrict__ b1,       // (64,)
    const float* __restrict__ b2,       // (128,)
    const float* __restrict__ b3,       // (256,)
    const uint4* __restrict__ wsf,      // packed W2/W3 fragments
    float*       __restrict__ out)      // (B,M,256)
{
    __shared__ uint4 h1v[ROWS * 64 * 2 / 16];    // 512 uint4  = 8 KB
    __shared__ uint4 h2v[ROWS * 128 * 2 / 16];   // 1024 uint4 = 16 KB

    const int tid = threadIdx.x;
    const int w   = tid >> 6;          // wave 0..3
    const int l   = tid & 63;
    const int q   = l >> 4;            // quad 0..3
    const int n   = l & 15;            // frag row/col index
    const int bm0 = blockIdx.x * G;

    // ---- B-fragments from ws (coalesced uint4) ----
    bf16x8 B2f[2][2];  float b2v[2];
    #pragma unroll
    for (int ct = 0; ct < 2; ++ct) {
        b2v[ct] = b2[w * 32 + ct * 16 + n];
        #pragma unroll
        for (int kt = 0; kt < 2; ++kt) {
            uint4 u = wsf[((w * 2 + ct) * 2 + kt) * 64 + l];
            B2f[ct][kt] = *(bf16x8*)&u;
        }
    }
    bf16x8 B3f[4][4];  float b3v[4];
    #pragma unroll
    for (int ct = 0; ct < 4; ++ct) {
        b3v[ct] = b3[w * 64 + ct * 16 + n];
        #pragma unroll
        for (int kt = 0; kt < 4; ++kt) {
            uint4 u = wsf[1024 + ((w * 4 + ct) * 4 + kt) * 64 + l];
            B3f[ct][kt] = *(bf16x8*)&u;
        }
    }

    // ---- gather + center-subtract (4 threads per row, redundant) ----
    const int r64 = tid & 63;                 // row 0..63
    {
        int bm = bm0 + (r64 >> 5);
        int bb = bm >> 11;
        int id = idx[(size_t)bm * Kn + (r64 & 31)];
        const float* p = xyz + ((size_t)bb * Nn + id) * 3;
        const float* c = centers + (size_t)bm * 3;
        float lx = p[0] - c[0], ly = p[1] - c[1], lz = p[2] - c[2];

        // ---- stage 1: thread computes 16 channels of its row; W1/b1 via
        //      wave-uniform s_loads (o4b forced scalar) ----
        const int o4b = __builtin_amdgcn_readfirstlane((tid >> 6) * 4);
        float h[16];
        #pragma unroll
        for (int i = 0; i < 4; ++i) {
            const float4* Wp = (const float4*)(W1 + (o4b + i) * 12);
            float4 wa = Wp[0], wb = Wp[1], wc = Wp[2];
            float4 bb4 = *(const float4*)(b1 + (o4b + i) * 4);
            h[4*i+0] = fmaxf(bb4.x + lx*wa.x + ly*wa.y + lz*wa.z, 0.f);
            h[4*i+1] = fmaxf(bb4.y + lx*wa.w + ly*wb.x + lz*wb.y, 0.f);
            h[4*i+2] = fmaxf(bb4.z + lx*wb.z + ly*wb.w + lz*wc.x, 0.f);
            h[4*i+3] = fmaxf(bb4.w + lx*wc.y + ly*wc.z + lz*wc.w, 0.f);
        }
        const int T = r64 >> 4, r = r64 & 15, j0 = (tid >> 6) * 2;
        #pragma unroll
        for (int jj = 0; jj < 2; ++jj) {
            bf16x8 v = pack8(&h[8 * jj]);
            h1v[T * 128 + (j0 + jj) * 16 + r] = *(uint4*)&v;
        }
    }
    __syncthreads();

    // ---- stage 2: h2 = relu(h1 @ W2^T + b2), wave owns 32 cols ----
    {
        ushort* h2s = (ushort*)h2v;
        #pragma unroll
        for (int rt = 0; rt < G * 2; ++rt) {
            uint4 a0u = h1v[rt * 128 + q * 16 + n];
            uint4 a1u = h1v[rt * 128 + (4 + q) * 16 + n];
            bf16x8 A0 = *(bf16x8*)&a0u, A1 = *(bf16x8*)&a1u;
            #pragma unroll
            for (int ct = 0; ct < 2; ++ct) {
                f32x4v c0 = {0.f, 0.f, 0.f, 0.f};
                c0 = __builtin_amdgcn_mfma_f32_16x16x32_bf16(A0, B2f[ct][0], c0, 0, 0, 0);
                c0 = __builtin_amdgcn_mfma_f32_16x16x32_bf16(A1, B2f[ct][1], c0, 0, 0, 0);
                int ch = w * 32 + ct * 16 + n;
                ushort* base = &h2s[rt * 2048 + (ch >> 3) * 128 + (ch & 7)];
                #pragma unroll
                for (int rp = 0; rp < 2; ++rp) {
                    float v0 = fmaxf(c0[2*rp+0] + b2v[ct], 0.f);
                    float v1 = fmaxf(c0[2*rp+1] + b2v[ct], 0.f);
                    unsigned pk = pk2(v0, v1);
                    base[(q * 4 + 2*rp)     * 8] = (ushort)pk;
                    base[(q * 4 + 2*rp + 1) * 8] = (ushort)(pk >> 16);
                }
            }
        }
    }
    __syncthreads();

    // ---- stage 3: wave owns 64 cols; fold rt-pair in regs, then 2 shfls ----
    {
        #pragma unroll
        for (int g = 0; g < G; ++g) {
            bf16x8 Ae[4], Ao[4];
            #pragma unroll
            for (int kt = 0; kt < 4; ++kt) {
                uint4 ae = h2v[(2*g)   * 256 + (kt * 4 + q) * 16 + n];
                uint4 ao = h2v[(2*g+1) * 256 + (kt * 4 + q) * 16 + n];
                Ae[kt] = *(bf16x8*)&ae;
                Ao[kt] = *(bf16x8*)&ao;
            }
            #pragma unroll
            for (int ct = 0; ct < 4; ++ct) {
                f32x4v Ce = {0.f, 0.f, 0.f, 0.f};
                f32x4v Co = {0.f, 0.f, 0.f, 0.f};
                #pragma unroll
                for (int kt = 0; kt < 4; ++kt) {
                    Ce = __builtin_amdgcn_mfma_f32_16x16x32_bf16(Ae[kt], B3f[ct][kt], Ce, 0, 0, 0);
                    Co = __builtin_amdgcn_mfma_f32_16x16x32_bf16(Ao[kt], B3f[ct][kt], Co, 0, 0, 0);
                }
                float v = fmaxf(fmaxf(fmaxf(Ce[0], Co[0]), fmaxf(Ce[1], Co[1])),
                                fmaxf(fmaxf(Ce[2], Co[2]), fmaxf(Ce[3], Co[3])));
                v = fmaxf(v, __shfl_xor(v, 16));
                v = fmaxf(v, __shfl_xor(v, 32));
                if (q == 0) {
                    out[(size_t)(bm0 + g) * EMB + w * 64 + ct * 16 + n] = v + b3v[ct];
                }
            }
        }
    }
}

extern "C" void kernel_launch(void* const* d_in, const int* in_sizes, int n_in,
                              void* d_out, int out_size, void* d_ws, size_t ws_size,
                              hipStream_t stream) {
    const float* xyz     = (const float*)d_in[0];
    const float* centers = (const float*)d_in[1];
    const int*   idx     = (const int*)  d_in[2];
    const float* W1      = (const float*)d_in[3];
    const float* b1      = (const float*)d_in[4];
    const float* W2      = (const float*)d_in[5];
    const float* b2      = (const float*)d_in[6];
    const float* W3      = (const float*)d_in[7];
    const float* b3      = (const float*)d_in[8];
    float*       out     = (float*)d_out;
    uint4*       ws      = (uint4*)d_ws;    // needs 5120*16 = 80 KB

    pe_pack<<<20, 256, 0, stream>>>(W2, W3, ws);
    pe_mfma<<<(Bn * Mn) / G, 256, 0, stream>>>(
        xyz, centers, idx, W1, b1, b2, b3, ws, out);
}